// Round 1
// baseline (1005.197 us; speedup 1.0000x reference)
//
#include <hip/hip_runtime.h>
#include <stdint.h>

#define N_NODES 50000
#define M_PAD   50048   // 391*128
#define R_REL   8
#define E_EDGES 100000
#define D_IN    768
#define D_H     256
#define N_CAT   2304    // 9*256 : [self | rel0..rel7]
#define LN_EPS  1e-5f

typedef __attribute__((ext_vector_type(8))) __bf16        bf16x8;
typedef __attribute__((ext_vector_type(4))) float         f32x4;
typedef __attribute__((ext_vector_type(8))) unsigned short u16x8;
typedef __attribute__((ext_vector_type(4))) unsigned short u16x4;

__device__ __forceinline__ float bf2f(unsigned short u) {
  union { float f; uint32_t i; } c; c.i = ((uint32_t)u) << 16; return c.f;
}
__device__ __forceinline__ unsigned short f2bf(float f) {
  uint32_t x = __float_as_uint(f);
  uint32_t r = (x + 0x7fffu + ((x >> 16) & 1u)) >> 16;   // RNE
  return (unsigned short)r;
}

// async global->LDS, 16B per lane. LDS dest is wave-uniform base + lane*16.
__device__ __forceinline__ void gload_lds16(const void* g, uint32_t lds_off) {
  __builtin_amdgcn_global_load_lds(
      (const __attribute__((address_space(1))) void*)(uintptr_t)g,
      (__attribute__((address_space(3))) void*)(uintptr_t)lds_off, 16, 0, 0);
}

// ---------------- CSR build ----------------
__global__ void k_deg(const int* __restrict__ tgt, int* __restrict__ deg) {
  int e = blockIdx.x * 256 + threadIdx.x;
  if (e >= R_REL * E_EDGES) return;
  int r = e / E_EDGES;
  atomicAdd(&deg[r * N_NODES + tgt[e]], 1);
}

__global__ __launch_bounds__(1024)
void k_scan(const int* __restrict__ deg, int* __restrict__ rowptr) {
  __shared__ int sh[1024];
  const int r = blockIdx.x, tid = threadIdx.x;
  const int* d = deg + r * N_NODES;
  int* rp = rowptr + r * (N_NODES + 1);
  int carry = 0;
  for (int base = 0; base < N_NODES; base += 1024) {
    const int i = base + tid;
    int v = (i < N_NODES) ? d[i] : 0;
    sh[tid] = v;
    __syncthreads();
    int run = v;
    for (int off = 1; off < 1024; off <<= 1) {
      int add = (tid >= off) ? sh[tid - off] : 0;
      __syncthreads();
      run += add;
      sh[tid] = run;
      __syncthreads();
    }
    if (i < N_NODES) rp[i] = carry + run - v;   // exclusive
    carry += sh[1023];
    __syncthreads();
  }
  if (tid == 0) rp[N_NODES] = carry;
}

__global__ void k_fill(const int* __restrict__ src, const int* __restrict__ tgt,
                       const float* __restrict__ nw, const int* __restrict__ rowptr,
                       int* __restrict__ cursor, int* __restrict__ elist,
                       float* __restrict__ ew) {
  int e = blockIdx.x * 256 + threadIdx.x;
  if (e >= R_REL * E_EDGES) return;
  int r = e / E_EDGES;
  int t = tgt[e], s = src[e];
  int pos = atomicAdd(&cursor[r * N_NODES + t], 1);
  int slot = r * E_EDGES + rowptr[r * (N_NODES + 1) + t] + pos;
  elist[slot] = s;
  ew[slot] = nw[s];
}

// ---------------- conversions ----------------
__global__ void k_cvt_x(const float* __restrict__ x, unsigned short* __restrict__ xb) {
  const size_t i = ((size_t)blockIdx.x * 256 + threadIdx.x) * 4;
  if (i >= (size_t)N_NODES * D_IN) return;
  const f32x4 v = *(const f32x4*)(x + i);
  u16x4 o = { f2bf(v[0]), f2bf(v[1]), f2bf(v[2]), f2bf(v[3]) };
  *(u16x4*)(xb + i) = o;
}

// Wt[n][k] = n<256 ? Wself[k][n] : Wrel[(n-256)>>8][k][n&255]   (bf16, [N_CAT][K])
__global__ void k_cvt_w(const float* __restrict__ Ws, const float* __restrict__ Wr,
                        unsigned short* __restrict__ Wt, int K) {
  int idx = blockIdx.x * 256 + threadIdx.x;
  if (idx >= N_CAT * K) return;
  int n = idx / K, k = idx - n * K;
  float v = (n < 256) ? Ws[k * 256 + n]
                      : Wr[(size_t)((n - 256) >> 8) * K * 256 + k * 256 + (n & 255)];
  Wt[idx] = f2bf(v);
}

// ---------------- bf16 MFMA GEMM: C[M_PAD,N_CAT] = A[M_PAD,K] @ Bt[N_CAT,K]^T ----------------
__global__ __launch_bounds__(256, 2)
void k_gemm(const unsigned short* __restrict__ A, const unsigned short* __restrict__ Bt,
            unsigned short* __restrict__ C, int K) {
  __shared__ __align__(16) char smem[32768];   // 8K A-tile + 8K B-tile; 32K epilogue repack
  const int tid  = threadIdx.x;
  const int wave = tid >> 6, lane = tid & 63;
  const int tileN = blockIdx.x * 128;          // N-major adjacency: blocks sharing A run together
  const int tileM = blockIdx.y * 128;
  const int wm = (wave >> 1) * 64, wn = (wave & 1) * 64;

  f32x4 acc[4][4] = {};

  const int srow = wave * 32 + (lane >> 2);    // staging row (0..127 with +16 for 2nd inst)
  const unsigned short* gA = A  + (size_t)(tileM + srow) * K + (lane & 3) * 8;
  const unsigned short* gB = Bt + (size_t)(tileN + srow) * K + (lane & 3) * 8;
  const uint32_t ldsA = (uint32_t)(uintptr_t)smem;
  const uint32_t ldsB = ldsA + 8192;
  const uint32_t lA0 = ldsA + (wave * 32) * 64;
  const uint32_t lB0 = ldsB + (wave * 32) * 64;
  const size_t rowstep = (size_t)16 * K;

  const int nk = K >> 5;
  for (int kt = 0; kt < nk; ++kt) {
    const int koff = kt * 32;
    __syncthreads();
    gload_lds16(gA + koff,           lA0);
    gload_lds16(gA + rowstep + koff, lA0 + 16 * 64);
    gload_lds16(gB + koff,           lB0);
    gload_lds16(gB + rowstep + koff, lB0 + 16 * 64);
    __syncthreads();
    const char* pA = smem        + (wm + (lane & 15)) * 64 + (lane >> 4) * 16;
    const char* pB = smem + 8192 + (wn + (lane & 15)) * 64 + (lane >> 4) * 16;
    bf16x8 af[4], bfr[4];
#pragma unroll
    for (int i = 0; i < 4; ++i) af[i]  = *(const bf16x8*)(pA + i * 1024);
#pragma unroll
    for (int j = 0; j < 4; ++j) bfr[j] = *(const bf16x8*)(pB + j * 1024);
#pragma unroll
    for (int i = 0; i < 4; ++i)
#pragma unroll
      for (int j = 0; j < 4; ++j)
        acc[i][j] = __builtin_amdgcn_mfma_f32_16x16x32_bf16(af[i], bfr[j], acc[i][j], 0, 0, 0);
  }

  // epilogue: AGPR -> LDS (bf16) -> coalesced 16B global stores
  __syncthreads();
  unsigned short* st = (unsigned short*)smem + wave * 4096;   // 64x64 u16 per wave
  const int rq = (lane >> 4) * 4, cq = lane & 15;
#pragma unroll
  for (int i = 0; i < 4; ++i)
#pragma unroll
    for (int j = 0; j < 4; ++j)
#pragma unroll
      for (int p = 0; p < 4; ++p)
        st[(i * 16 + rq + p) * 64 + j * 16 + cq] = f2bf(acc[i][j][p]);
  __syncthreads();
#pragma unroll
  for (int pass = 0; pass < 8; ++pass) {
    const int row = pass * 8 + (lane >> 3);
    u16x8 v = *(const u16x8*)(st + row * 64 + (lane & 7) * 8);
    size_t off = (size_t)(tileM + wm + row) * N_CAT + tileN + wn + (lane & 7) * 8;
    *(u16x8*)(C + off) = v;
  }
}

// ---------------- fused gather + mean + self + bias + ReLU + LayerNorm ----------------
// one wave per node; lane holds 4 of 256 channels
template <int FINAL>
__global__ __launch_bounds__(256)
void k_gather_ln(const unsigned short* __restrict__ Y, const int* __restrict__ rowptr,
                 const int* __restrict__ elist, const float* __restrict__ ew,
                 const float* __restrict__ bias, const float* __restrict__ g,
                 const float* __restrict__ bln, void* __restrict__ out) {
  const int wave = threadIdx.x >> 6, lane = threadIdx.x & 63;
  const int t = blockIdx.x * 4 + wave;
  if (t >= N_NODES) return;
  const int c0 = lane * 4;

  float a0, a1, a2, a3;
  {
    u16x4 sv = *(const u16x4*)(Y + (size_t)t * N_CAT + c0);
    a0 = bf2f(sv[0]) + bias[c0 + 0];
    a1 = bf2f(sv[1]) + bias[c0 + 1];
    a2 = bf2f(sv[2]) + bias[c0 + 2];
    a3 = bf2f(sv[3]) + bias[c0 + 3];
  }
#pragma unroll
  for (int r = 0; r < R_REL; ++r) {
    const int rp0 = rowptr[r * (N_NODES + 1) + t];
    const int rp1 = rowptr[r * (N_NODES + 1) + t + 1];
    if (rp0 == rp1) continue;
    float r0 = 0, r1 = 0, r2 = 0, r3 = 0;
    const int base = r * E_EDGES;
    const size_t colr = (size_t)(1 + r) * 256 + c0;
    for (int idx = rp0; idx < rp1; ++idx) {
      const int s = elist[base + idx];
      const float w = ew[base + idx];
      u16x4 v = *(const u16x4*)(Y + (size_t)s * N_CAT + colr);
      r0 += w * bf2f(v[0]); r1 += w * bf2f(v[1]);
      r2 += w * bf2f(v[2]); r3 += w * bf2f(v[3]);
    }
    const float inv = 1.0f / (float)(rp1 - rp0);
    a0 += inv * r0; a1 += inv * r1; a2 += inv * r2; a3 += inv * r3;
  }
  a0 = fmaxf(a0, 0.f); a1 = fmaxf(a1, 0.f); a2 = fmaxf(a2, 0.f); a3 = fmaxf(a3, 0.f);

  float s1 = a0 + a1 + a2 + a3;
#pragma unroll
  for (int off = 32; off > 0; off >>= 1) s1 += __shfl_xor(s1, off, 64);
  const float mu = s1 * (1.f / 256.f);
  const float d0 = a0 - mu, d1 = a1 - mu, d2 = a2 - mu, d3 = a3 - mu;
  float s2 = d0 * d0 + d1 * d1 + d2 * d2 + d3 * d3;
#pragma unroll
  for (int off = 32; off > 0; off >>= 1) s2 += __shfl_xor(s2, off, 64);
  const float rs = rsqrtf(s2 * (1.f / 256.f) + LN_EPS);
  const float o0 = d0 * rs * g[c0 + 0] + bln[c0 + 0];
  const float o1 = d1 * rs * g[c0 + 1] + bln[c0 + 1];
  const float o2 = d2 * rs * g[c0 + 2] + bln[c0 + 2];
  const float o3 = d3 * rs * g[c0 + 3] + bln[c0 + 3];
  if (FINAL) {
    f32x4 o = { o0, o1, o2, o3 };
    *(f32x4*)((float*)out + (size_t)t * 256 + c0) = o;
  } else {
    u16x4 o = { f2bf(o0), f2bf(o1), f2bf(o2), f2bf(o3) };
    *(u16x4*)((unsigned short*)out + (size_t)t * 256 + c0) = o;
  }
}

// ---------------- launch ----------------
extern "C" void kernel_launch(void* const* d_in, const int* in_sizes, int n_in,
                              void* d_out, int out_size, void* d_ws, size_t ws_size,
                              hipStream_t stream) {
  (void)in_sizes; (void)n_in; (void)out_size; (void)ws_size;
  const float* x   = (const float*)d_in[0];
  const float* nw  = (const float*)d_in[1];
  const int*   esrc = (const int*)d_in[2];
  const int*   etgt = (const int*)d_in[3];
  const float* Wr0 = (const float*)d_in[4];
  const float* Ws0 = (const float*)d_in[5];
  const float* Wb0 = (const float*)d_in[6];
  const float* g0  = (const float*)d_in[7];
  const float* b0  = (const float*)d_in[8];
  const float* Wr1 = (const float*)d_in[9];
  const float* Ws1 = (const float*)d_in[10];
  const float* Wb1 = (const float*)d_in[11];
  const float* g1  = (const float*)d_in[12];
  const float* b1  = (const float*)d_in[13];

  char* p = (char*)d_ws;
  auto carve = [&](size_t bytes) {
    char* q = p;
    p += (bytes + 511) & ~(size_t)511;
    return q;
  };
  unsigned short* Y   = (unsigned short*)carve((size_t)M_PAD * N_CAT * 2);  // 230.6 MB
  unsigned short* xb  = (unsigned short*)carve((size_t)M_PAD * D_IN * 2);   //  76.9 MB
  unsigned short* h   = (unsigned short*)carve((size_t)M_PAD * D_H * 2);    //  25.6 MB
  unsigned short* Wt0 = (unsigned short*)carve((size_t)N_CAT * D_IN * 2);
  unsigned short* Wt1 = (unsigned short*)carve((size_t)N_CAT * D_H * 2);
  int*   deg    = (int*)carve((size_t)R_REL * N_NODES * 4);
  int*   cursor = (int*)carve((size_t)R_REL * N_NODES * 4);
  int*   rowptr = (int*)carve((size_t)R_REL * (N_NODES + 1) * 4);
  int*   elist  = (int*)carve((size_t)R_REL * E_EDGES * 4);
  float* ewt    = (float*)carve((size_t)R_REL * E_EDGES * 4);

  // CSR build (shared by both layers)
  hipMemsetAsync(deg, 0, (size_t)R_REL * N_NODES * 4, stream);
  hipMemsetAsync(cursor, 0, (size_t)R_REL * N_NODES * 4, stream);
  k_deg<<<(R_REL * E_EDGES + 255) / 256, 256, 0, stream>>>(etgt, deg);
  k_scan<<<R_REL, 1024, 0, stream>>>(deg, rowptr);
  k_fill<<<(R_REL * E_EDGES + 255) / 256, 256, 0, stream>>>(esrc, etgt, nw, rowptr,
                                                            cursor, elist, ewt);
  // conversions
  k_cvt_x<<<(N_NODES * D_IN / 4 + 255) / 256, 256, 0, stream>>>(x, xb);
  k_cvt_w<<<(N_CAT * D_IN + 255) / 256, 256, 0, stream>>>(Ws0, Wr0, Wt0, D_IN);
  k_cvt_w<<<(N_CAT * D_H + 255) / 256, 256, 0, stream>>>(Ws1, Wr1, Wt1, D_H);

  dim3 gg(N_CAT / 128, M_PAD / 128);
  // layer 0
  k_gemm<<<gg, 256, 0, stream>>>(xb, Wt0, Y, D_IN);
  k_gather_ln<0><<<N_NODES / 4, 256, 0, stream>>>(Y, rowptr, elist, ewt, Wb0, g0, b0, h);
  // layer 1
  k_gemm<<<gg, 256, 0, stream>>>(h, Wt1, Y, D_H);
  k_gather_ln<1><<<N_NODES / 4, 256, 0, stream>>>(Y, rowptr, elist, ewt, Wb1, g1, b1, d_out);
}

// Round 2
// 894.741 us; speedup vs baseline: 1.1235x; 1.1235x over previous
//
#include <hip/hip_runtime.h>
#include <stdint.h>

#define N_NODES 50000
#define M_PAD   50048   // 391*128
#define R_REL   8
#define E_EDGES 100000
#define D_IN    768
#define D_H     256
#define N_CAT   2304    // 9*256 : [self | rel0..rel7]
#define LN_EPS  1e-5f

#define TILES_N 18      // N_CAT/128
#define TILES_M 391     // M_PAD/128
#define T_TOT   (TILES_N * TILES_M)          // 7038
#define T_PER_XCD ((T_TOT + 7) / 8)          // 880
#define NCHUNK  49      // ceil(50000/1024)

typedef __attribute__((ext_vector_type(8))) __bf16        bf16x8;
typedef __attribute__((ext_vector_type(4))) float         f32x4;
typedef __attribute__((ext_vector_type(8))) unsigned short u16x8;
typedef __attribute__((ext_vector_type(4))) unsigned short u16x4;
typedef __attribute__((ext_vector_type(4))) int            i32x4;

__device__ __forceinline__ float bf2f(unsigned short u) {
  union { float f; uint32_t i; } c; c.i = ((uint32_t)u) << 16; return c.f;
}
__device__ __forceinline__ unsigned short f2bf(float f) {
  uint32_t x = __float_as_uint(f);
  uint32_t r = (x + 0x7fffu + ((x >> 16) & 1u)) >> 16;   // RNE
  return (unsigned short)r;
}

__device__ __forceinline__ void gload_lds16(const void* g, uint32_t lds_off) {
  __builtin_amdgcn_global_load_lds(
      (const __attribute__((address_space(1))) void*)(uintptr_t)g,
      (__attribute__((address_space(3))) void*)(uintptr_t)lds_off, 16, 0, 0);
}

// ---------------- CSR build ----------------
__global__ void k_deg(const int* __restrict__ tgt, int* __restrict__ deg) {
  int e = blockIdx.x * 256 + threadIdx.x;
  if (e >= R_REL * E_EDGES) return;
  int r = e / E_EDGES;
  atomicAdd(&deg[r * N_NODES + tgt[e]], 1);
}

// partial scan: each block scans its 1024-chunk, writes partial rowptr + block sum
__global__ __launch_bounds__(256)
void k_scan1(const int* __restrict__ deg, int* __restrict__ rowptr,
             int* __restrict__ bsum) {
  __shared__ int wtot[4];
  const int r = blockIdx.y, chunk = blockIdx.x, tid = threadIdx.x;
  const int wave = tid >> 6, lane = tid & 63;
  const int i0 = chunk * 1024 + tid * 4;
  int v0 = 0, v1 = 0, v2 = 0, v3 = 0;
  const int* d = deg + r * N_NODES;
  if (chunk != NCHUNK - 1) {
    i32x4 v = *(const i32x4*)(d + i0);
    v0 = v[0]; v1 = v[1]; v2 = v[2]; v3 = v[3];
  } else {
    if (i0 + 0 < N_NODES) v0 = d[i0 + 0];
    if (i0 + 1 < N_NODES) v1 = d[i0 + 1];
    if (i0 + 2 < N_NODES) v2 = d[i0 + 2];
    if (i0 + 3 < N_NODES) v3 = d[i0 + 3];
  }
  const int tsum = v0 + v1 + v2 + v3;
  int inc = tsum;
#pragma unroll
  for (int off = 1; off < 64; off <<= 1) {
    int t = __shfl_up(inc, off, 64);
    if (lane >= off) inc += t;
  }
  if (lane == 63) wtot[wave] = inc;
  __syncthreads();
  int woff = 0;
#pragma unroll
  for (int w = 0; w < 4; ++w) woff += (w < wave) ? wtot[w] : 0;
  int excl = woff + inc - tsum;
  int* rp = rowptr + r * (N_NODES + 1);
  if (i0 + 0 < N_NODES) rp[i0 + 0] = excl;
  if (i0 + 1 < N_NODES) rp[i0 + 1] = excl + v0;
  if (i0 + 2 < N_NODES) rp[i0 + 2] = excl + v0 + v1;
  if (i0 + 3 < N_NODES) rp[i0 + 3] = excl + v0 + v1 + v2;
  if (tid == 0) bsum[r * NCHUNK + chunk] = wtot[0] + wtot[1] + wtot[2] + wtot[3];
}

// scan the 49 chunk sums per relation (1 wave per relation)
__global__ __launch_bounds__(512)
void k_scan2(const int* __restrict__ bsum, int* __restrict__ chunkoff,
             int* __restrict__ rowptr) {
  const int r = threadIdx.x >> 6, lane = threadIdx.x & 63;
  int v = (lane < NCHUNK) ? bsum[r * NCHUNK + lane] : 0;
  int inc = v;
#pragma unroll
  for (int off = 1; off < 64; off <<= 1) {
    int t = __shfl_up(inc, off, 64);
    if (lane >= off) inc += t;
  }
  if (lane < NCHUNK) chunkoff[r * NCHUNK + lane] = inc - v;   // exclusive
  if (lane == NCHUNK - 1) rowptr[r * (N_NODES + 1) + N_NODES] = inc;
}

__global__ __launch_bounds__(256)
void k_scan3(const int* __restrict__ chunkoff, int* __restrict__ rowptr) {
  const int r = blockIdx.y, chunk = blockIdx.x;
  if (chunk == 0) return;
  const int off = chunkoff[r * NCHUNK + chunk];
  const int i0 = chunk * 1024 + threadIdx.x * 4;
  int* rp = rowptr + r * (N_NODES + 1);
#pragma unroll
  for (int j = 0; j < 4; ++j)
    if (i0 + j < N_NODES) rp[i0 + j] += off;
}

// fill CSR adjacency: e2[slot] = {src, bits(node_weight[src])}
__global__ void k_fill(const int* __restrict__ src, const int* __restrict__ tgt,
                       const float* __restrict__ nw, const int* __restrict__ rowptr,
                       int* __restrict__ cursor, int2* __restrict__ e2) {
  int e = blockIdx.x * 256 + threadIdx.x;
  if (e >= R_REL * E_EDGES) return;
  int r = e / E_EDGES;
  int t = tgt[e], s = src[e];
  int pos = atomicAdd(&cursor[r * N_NODES + t], 1);
  int slot = r * E_EDGES + rowptr[r * (N_NODES + 1) + t] + pos;
  e2[slot] = make_int2(s, __float_as_int(nw[s]));
}

// ---------------- conversions ----------------
__global__ void k_cvt_x(const float* __restrict__ x, unsigned short* __restrict__ xb) {
  const size_t i = ((size_t)blockIdx.x * 256 + threadIdx.x) * 4;
  if (i >= (size_t)N_NODES * D_IN) return;
  const f32x4 v = *(const f32x4*)(x + i);
  u16x4 o = { f2bf(v[0]), f2bf(v[1]), f2bf(v[2]), f2bf(v[3]) };
  *(u16x4*)(xb + i) = o;
}

// Wt[n][k] = n<256 ? Wself[k][n] : Wrel[(n-256)>>8][k][n&255]   (bf16, [N_CAT][K])
__global__ void k_cvt_w(const float* __restrict__ Ws, const float* __restrict__ Wr,
                        unsigned short* __restrict__ Wt, int K) {
  int idx = blockIdx.x * 256 + threadIdx.x;
  if (idx >= N_CAT * K) return;
  int n = idx / K, k = idx - n * K;
  float v = (n < 256) ? Ws[k * 256 + n]
                      : Wr[(size_t)((n - 256) >> 8) * K * 256 + k * 256 + (n & 255)];
  Wt[idx] = f2bf(v);
}

// ---------------- bf16 MFMA GEMM: C[M_PAD,N_CAT] = A[M_PAD,K] @ Bt[N_CAT,K]^T --------
// XCD-swizzled 1-D grid: each XCD owns a contiguous band of M rows (A reuse in its L2).
// LDS k-chunk XOR swizzle: slot s of row r holds k-chunk (s-r)&3 -> 2-way banks (free).
__global__ __launch_bounds__(256, 2)
void k_gemm(const unsigned short* __restrict__ A, const unsigned short* __restrict__ Bt,
            unsigned short* __restrict__ C, int K) {
  const int tile = (blockIdx.x & 7) * T_PER_XCD + (blockIdx.x >> 3);
  if (tile >= T_TOT) return;
  const int tileM = (tile / TILES_N) * 128;
  const int tileN = (tile % TILES_N) * 128;

  __shared__ __align__(16) char smem[32768];
  const int tid  = threadIdx.x;
  const int wave = tid >> 6, lane = tid & 63;
  const int wm = (wave >> 1) * 64, wn = (wave & 1) * 64;

  f32x4 acc[4][4] = {};

  // staging: lane (wave,l) covers row wave*32 + (l>>2) (+16 for 2nd inst), slot l&3
  const int srow = wave * 32 + (lane >> 2);
  const int kchunk = ((lane & 3) - ((lane >> 2) & 3)) & 3;   // content(r,s)=(s-r)&3
  const unsigned short* gA = A  + (size_t)(tileM + srow) * K + kchunk * 8;
  const unsigned short* gB = Bt + (size_t)(tileN + srow) * K + kchunk * 8;
  const uint32_t ldsA = (uint32_t)(uintptr_t)smem;
  const uint32_t ldsB = ldsA + 8192;
  const uint32_t lA0 = ldsA + (wave * 32) * 64;
  const uint32_t lB0 = ldsB + (wave * 32) * 64;
  const size_t rowstep = (size_t)16 * K;

  // fragment read: phase p=lane>>4 of row r reads slot (p+r)&3
  const int slot = (((lane >> 4) + (lane & 3)) & 3) * 16;
  const char* pA = smem        + (wm + (lane & 15)) * 64 + slot;
  const char* pB = smem + 8192 + (wn + (lane & 15)) * 64 + slot;

  const int nk = K >> 5;
  for (int kt = 0; kt < nk; ++kt) {
    const int koff = kt * 32;
    __syncthreads();
    gload_lds16(gA + koff,           lA0);
    gload_lds16(gA + rowstep + koff, lA0 + 16 * 64);
    gload_lds16(gB + koff,           lB0);
    gload_lds16(gB + rowstep + koff, lB0 + 16 * 64);
    __syncthreads();
    bf16x8 af[4], bfr[4];
#pragma unroll
    for (int i = 0; i < 4; ++i) af[i]  = *(const bf16x8*)(pA + i * 1024);
#pragma unroll
    for (int j = 0; j < 4; ++j) bfr[j] = *(const bf16x8*)(pB + j * 1024);
#pragma unroll
    for (int i = 0; i < 4; ++i)
#pragma unroll
      for (int j = 0; j < 4; ++j)
        acc[i][j] = __builtin_amdgcn_mfma_f32_16x16x32_bf16(af[i], bfr[j], acc[i][j], 0, 0, 0);
  }

  // epilogue: AGPR -> LDS (bf16) -> coalesced 16B global stores
  __syncthreads();
  unsigned short* st = (unsigned short*)smem + wave * 4096;   // 64x64 u16 per wave
  const int rq = (lane >> 4) * 4, cq = lane & 15;
#pragma unroll
  for (int i = 0; i < 4; ++i)
#pragma unroll
    for (int j = 0; j < 4; ++j)
#pragma unroll
      for (int p = 0; p < 4; ++p)
        st[(i * 16 + rq + p) * 64 + j * 16 + cq] = f2bf(acc[i][j][p]);
  __syncthreads();
#pragma unroll
  for (int pass = 0; pass < 8; ++pass) {
    const int row = pass * 8 + (lane >> 3);
    u16x8 v = *(const u16x8*)(st + row * 64 + (lane & 7) * 8);
    size_t off = (size_t)(tileM + wm + row) * N_CAT + tileN + wn + (lane & 7) * 8;
    *(u16x8*)(C + off) = v;
  }
}

// ---------------- fused gather + mean + self + bias + ReLU + LayerNorm ----------------
// one wave per node; lane holds 4 of 256 channels
template <int FINAL>
__global__ __launch_bounds__(256)
void k_gather_ln(const unsigned short* __restrict__ Y, const int* __restrict__ rowptr,
                 const int2* __restrict__ e2, const float* __restrict__ bias,
                 const float* __restrict__ g, const float* __restrict__ bln,
                 void* __restrict__ out) {
  const int wave = threadIdx.x >> 6, lane = threadIdx.x & 63;
  const int t = blockIdx.x * 4 + wave;
  if (t >= N_NODES) return;
  const int c0 = lane * 4;

  float a0, a1, a2, a3;
  {
    u16x4 sv = *(const u16x4*)(Y + (size_t)t * N_CAT + c0);
    a0 = bf2f(sv[0]) + bias[c0 + 0];
    a1 = bf2f(sv[1]) + bias[c0 + 1];
    a2 = bf2f(sv[2]) + bias[c0 + 2];
    a3 = bf2f(sv[3]) + bias[c0 + 3];
  }
#pragma unroll
  for (int r = 0; r < R_REL; ++r) {
    const int rp0 = rowptr[r * (N_NODES + 1) + t];
    const int rp1 = rowptr[r * (N_NODES + 1) + t + 1];
    if (rp0 == rp1) continue;
    float r0 = 0, r1 = 0, r2 = 0, r3 = 0;
    float q0 = 0, q1 = 0, q2 = 0, q3 = 0;
    const int base = r * E_EDGES;
    const size_t colr = (size_t)(1 + r) * 256 + c0;
    int idx = rp0;
    for (; idx + 2 <= rp1; idx += 2) {
      const int2 p0 = e2[base + idx];
      const int2 p1 = e2[base + idx + 1];
      const float w0 = __int_as_float(p0.y);
      const float w1 = __int_as_float(p1.y);
      u16x4 v0 = *(const u16x4*)(Y + (size_t)p0.x * N_CAT + colr);
      u16x4 v1 = *(const u16x4*)(Y + (size_t)p1.x * N_CAT + colr);
      r0 += w0 * bf2f(v0[0]); r1 += w0 * bf2f(v0[1]);
      r2 += w0 * bf2f(v0[2]); r3 += w0 * bf2f(v0[3]);
      q0 += w1 * bf2f(v1[0]); q1 += w1 * bf2f(v1[1]);
      q2 += w1 * bf2f(v1[2]); q3 += w1 * bf2f(v1[3]);
    }
    if (idx < rp1) {
      const int2 p0 = e2[base + idx];
      const float w0 = __int_as_float(p0.y);
      u16x4 v0 = *(const u16x4*)(Y + (size_t)p0.x * N_CAT + colr);
      r0 += w0 * bf2f(v0[0]); r1 += w0 * bf2f(v0[1]);
      r2 += w0 * bf2f(v0[2]); r3 += w0 * bf2f(v0[3]);
    }
    const float inv = 1.0f / (float)(rp1 - rp0);
    a0 += inv * (r0 + q0); a1 += inv * (r1 + q1);
    a2 += inv * (r2 + q2); a3 += inv * (r3 + q3);
  }
  a0 = fmaxf(a0, 0.f); a1 = fmaxf(a1, 0.f); a2 = fmaxf(a2, 0.f); a3 = fmaxf(a3, 0.f);

  float s1 = a0 + a1 + a2 + a3;
#pragma unroll
  for (int off = 32; off > 0; off >>= 1) s1 += __shfl_xor(s1, off, 64);
  const float mu = s1 * (1.f / 256.f);
  const float d0 = a0 - mu, d1 = a1 - mu, d2 = a2 - mu, d3 = a3 - mu;
  float s2 = d0 * d0 + d1 * d1 + d2 * d2 + d3 * d3;
#pragma unroll
  for (int off = 32; off > 0; off >>= 1) s2 += __shfl_xor(s2, off, 64);
  const float rs = rsqrtf(s2 * (1.f / 256.f) + LN_EPS);
  const float o0 = d0 * rs * g[c0 + 0] + bln[c0 + 0];
  const float o1 = d1 * rs * g[c0 + 1] + bln[c0 + 1];
  const float o2 = d2 * rs * g[c0 + 2] + bln[c0 + 2];
  const float o3 = d3 * rs * g[c0 + 3] + bln[c0 + 3];
  if (FINAL) {
    f32x4 o = { o0, o1, o2, o3 };
    *(f32x4*)((float*)out + (size_t)t * 256 + c0) = o;
  } else {
    u16x4 o = { f2bf(o0), f2bf(o1), f2bf(o2), f2bf(o3) };
    *(u16x4*)((unsigned short*)out + (size_t)t * 256 + c0) = o;
  }
}

// ---------------- launch ----------------
extern "C" void kernel_launch(void* const* d_in, const int* in_sizes, int n_in,
                              void* d_out, int out_size, void* d_ws, size_t ws_size,
                              hipStream_t stream) {
  (void)in_sizes; (void)n_in; (void)out_size; (void)ws_size;
  const float* x   = (const float*)d_in[0];
  const float* nw  = (const float*)d_in[1];
  const int*   esrc = (const int*)d_in[2];
  const int*   etgt = (const int*)d_in[3];
  const float* Wr0 = (const float*)d_in[4];
  const float* Ws0 = (const float*)d_in[5];
  const float* Wb0 = (const float*)d_in[6];
  const float* g0  = (const float*)d_in[7];
  const float* b0  = (const float*)d_in[8];
  const float* Wr1 = (const float*)d_in[9];
  const float* Ws1 = (const float*)d_in[10];
  const float* Wb1 = (const float*)d_in[11];
  const float* g1  = (const float*)d_in[12];
  const float* b1  = (const float*)d_in[13];

  char* p = (char*)d_ws;
  auto carve = [&](size_t bytes) {
    char* q = p;
    p += (bytes + 511) & ~(size_t)511;
    return q;
  };
  unsigned short* Y   = (unsigned short*)carve((size_t)M_PAD * N_CAT * 2);  // 230.6 MB
  unsigned short* xb  = (unsigned short*)carve((size_t)M_PAD * D_IN * 2);   //  76.9 MB
  unsigned short* h   = (unsigned short*)carve((size_t)M_PAD * D_H * 2);    //  25.6 MB
  unsigned short* Wt0 = (unsigned short*)carve((size_t)N_CAT * D_IN * 2);
  unsigned short* Wt1 = (unsigned short*)carve((size_t)N_CAT * D_H * 2);
  int*   deg     = (int*)carve((size_t)R_REL * N_NODES * 4);
  int*   cursor  = (int*)carve((size_t)R_REL * N_NODES * 4);
  int*   rowptr  = (int*)carve((size_t)R_REL * (N_NODES + 1) * 4);
  int*   bsum    = (int*)carve((size_t)R_REL * NCHUNK * 4);
  int*   chunkoff= (int*)carve((size_t)R_REL * NCHUNK * 4);
  int2*  e2      = (int2*)carve((size_t)R_REL * E_EDGES * 8);

  // CSR build (shared by both layers)
  hipMemsetAsync(deg, 0, (size_t)R_REL * N_NODES * 4, stream);
  hipMemsetAsync(cursor, 0, (size_t)R_REL * N_NODES * 4, stream);
  k_deg<<<(R_REL * E_EDGES + 255) / 256, 256, 0, stream>>>(etgt, deg);
  k_scan1<<<dim3(NCHUNK, R_REL), 256, 0, stream>>>(deg, rowptr, bsum);
  k_scan2<<<1, 512, 0, stream>>>(bsum, chunkoff, rowptr);
  k_scan3<<<dim3(NCHUNK, R_REL), 256, 0, stream>>>(chunkoff, rowptr);
  k_fill<<<(R_REL * E_EDGES + 255) / 256, 256, 0, stream>>>(esrc, etgt, nw, rowptr,
                                                            cursor, e2);
  // conversions
  k_cvt_x<<<(N_NODES * D_IN / 4 + 255) / 256, 256, 0, stream>>>(x, xb);
  k_cvt_w<<<(N_CAT * D_IN + 255) / 256, 256, 0, stream>>>(Ws0, Wr0, Wt0, D_IN);
  k_cvt_w<<<(N_CAT * D_H + 255) / 256, 256, 0, stream>>>(Ws1, Wr1, Wt1, D_H);

  const int nblk = 8 * T_PER_XCD;   // 7040, XCD-swizzled in-kernel
  // layer 0
  k_gemm<<<nblk, 256, 0, stream>>>(xb, Wt0, Y, D_IN);
  k_gather_ln<0><<<N_NODES / 4, 256, 0, stream>>>(Y, rowptr, e2, Wb0, g0, b0, h);
  // layer 1
  k_gemm<<<nblk, 256, 0, stream>>>(h, Wt1, Y, D_H);
  k_gather_ln<1><<<N_NODES / 4, 256, 0, stream>>>(Y, rowptr, e2, Wb1, g1, b1, d_out);
}